// Round 9
// baseline (161734.570 us; speedup 1.0000x reference)
//
#include <hip/hip_runtime.h>
#include <cstdint>

#define BATCH 4096
#define LATENT 128
#define RNN 512
#define CODE 512
#define DISC 64
#define NSEG 64
#define UNPACK_COLS 130  // LATENT + INPUT

// ------------- threefry2x32, JAX partitionable mode, key = (0, 42) -----------
__device__ __forceinline__ uint32_t rotl32(uint32_t x, uint32_t r) {
  return (x << r) | (x >> (32u - r));
}

__device__ __forceinline__ uint32_t threefry_bits(uint32_t n) {
  const uint32_t k0 = 0u, k1 = 42u;
  const uint32_t ks2 = k0 ^ k1 ^ 0x1BD11BDAu;
  uint32_t x0 = 0u, x1 = n;
  x0 += k0; x1 += k1;
#define TF_ROUND(r) { x0 += x1; x1 = rotl32(x1, r); x1 ^= x0; }
  TF_ROUND(13) TF_ROUND(15) TF_ROUND(26) TF_ROUND(6)
  x0 += k1;  x1 += ks2 + 1u;
  TF_ROUND(17) TF_ROUND(29) TF_ROUND(16) TF_ROUND(24)
  x0 += ks2; x1 += k0 + 2u;
  TF_ROUND(13) TF_ROUND(15) TF_ROUND(26) TF_ROUND(6)
  x0 += k0;  x1 += k1 + 3u;
  TF_ROUND(17) TF_ROUND(29) TF_ROUND(16) TF_ROUND(24)
  x0 += k1;  x1 += ks2 + 4u;
  TF_ROUND(13) TF_ROUND(15) TF_ROUND(26) TF_ROUND(6)
  x0 += ks2; x1 += k0 + 5u;
#undef TF_ROUND
  return x0 ^ x1;
}

__device__ __forceinline__ float sigmoidf_(float v) {
  return 1.0f / (1.0f + expf(-v));
}

// ---------------- base = latent @ W_unpack[:, :128]^T + b_unpack --------------
__global__ __launch_bounds__(256) void base_kernel(
    const float* __restrict__ latent, const float* __restrict__ Wu,
    const float* __restrict__ bu, float* __restrict__ base) {
  __shared__ float lrow[LATENT];
  const int b = blockIdx.x;
  if (threadIdx.x < LATENT) lrow[threadIdx.x] = latent[b * LATENT + threadIdx.x];
  __syncthreads();
  for (int n = threadIdx.x; n < CODE; n += 256) {
    const float* wr = Wu + (size_t)n * UNPACK_COLS;
    float acc = 0.f;
#pragma unroll 8
    for (int k = 0; k < LATENT; ++k) acc += lrow[k] * wr[k];
    base[(size_t)b * CODE + n] = acc + bu[n];
  }
}

// ---------------- x = tanh(base + angle * W_unpack[:, 128]) -------------------
__global__ __launch_bounds__(256) void x_kernel(
    const float* __restrict__ base, const float* __restrict__ angle,
    const float* __restrict__ Wu, float* __restrict__ xo) {
  const int idx = blockIdx.x * 256 + threadIdx.x;
  const int b = idx >> 9;
  const int n = idx & 511;
  xo[idx] = tanhf(base[idx] + angle[b] * Wu[(size_t)n * UNPACK_COLS + 128]);
}

// ----- fused: gates = A1@W1^T + A2@W2^T + b1 + b2 ; (h,c) = LSTM(gates, c) ----
// Wave-uniform A (global, ping-pong prefetch, never touches LDS) + W-only LDS.
// Per kk a wave issues 2 contiguous-1024B ds_read_b128 per 64 FMA-instrs ->
// per-CU LDS demand (8 waves: 2*16 reads + 8 writes)*12 = 3840 cyc < FMA 4096
// cyc per 16-k step: FMA-issue-bound (r3-r7 had 4 reads/kk -> LDS-bound 1.5x).
// Block = 256 thr = 4 waves; wave owns 8 rows x 512 tile-cols; lane owns
// cols {g0*128+4(l&31)} (gate g0=l>>5) and +256 (gate 2+g0): lane-pair l^32
// exchanges (i,g)/(f,o) -> r7-verified LSTM epilogue.  Grid (4,128) = 2
// blocks/CU.  k strictly ascending, seg-major: bit-identical accumulation.
__global__ __launch_bounds__(256, 2) void gemm_lstm(
    const float* __restrict__ A1, const float* __restrict__ W1,
    const float* __restrict__ A2, const float* __restrict__ W2,
    const float* __restrict__ b1, const float* __restrict__ b2,
    float* __restrict__ c_io, float* __restrict__ h_out) {
  __shared__ __align__(16) float Ws[16 * 512];  // 32 KB, [k][tilecol]
  const int tid = threadIdx.x;
  const int l = tid & 63;
  const int wv = tid >> 6;                 // 0..3
  const int bx = blockIdx.x;               // 0..3 (128 rnn-cols each)
  const int rowBase = blockIdx.y * 32;
  const int g0 = l >> 5;

  // W staging rows: lane l owns tile-cols 256c + 4l + r (c in {0,1}, r in 0..3)
  int wrow[2][4];
#pragma unroll
  for (int c = 0; c < 2; ++c)
#pragma unroll
    for (int r = 0; r < 4; ++r) {
      const int t = 256 * c + 4 * l + r;
      wrow[c][r] = ((t >> 7) * RNN) + (bx << 7) + (t & 127);
    }

  const float* __restrict__ a1base = A1 + (size_t)(rowBase + wv * 8) * RNN;
  const float* __restrict__ a2base = A2 + (size_t)(rowBase + wv * 8) * RNN;

  float acc[8][8];
#pragma unroll
  for (int i = 0; i < 8; ++i)
#pragma unroll
    for (int j = 0; j < 8; ++j) acc[i][j] = 0.f;

  float4 afA[8], afB[8];

  // flat A-chunk index t in [0,256): seg = t>>7, k0 = ((t>>2)&31)*16, c4 = t&3
#define PF(dst, tn)                                                            \
  {                                                                            \
    if ((tn) < 256) {                                                          \
      const float* __restrict__ bp = ((tn)&128) ? a2base : a1base;             \
      const int off = (((tn) >> 2) & 31) * 16 + ((tn)&3) * 4;                  \
      _Pragma("unroll") for (int i = 0; i < 8; ++i)                            \
          dst[i] = *(const float4*)&bp[(size_t)i * RNN + off];                 \
    }                                                                          \
  }

#define COMPUTE_C4(buf, c4)                                                    \
  {                                                                            \
    _Pragma("unroll") for (int kk = 0; kk < 4; ++kk) {                         \
      const int krow = ((c4)*4 + kk) * 512;                                    \
      const float4 wA = *(const float4*)&Ws[krow + g0 * 128 + 4 * (l & 31)];   \
      const float4 wB =                                                        \
          *(const float4*)&Ws[krow + 256 + g0 * 128 + 4 * (l & 31)];           \
      _Pragma("unroll") for (int i = 0; i < 8; ++i) {                          \
        const float a = ((const float*)&buf[i])[kk];                           \
        acc[i][0] += a * wA.x; acc[i][1] += a * wA.y;                          \
        acc[i][2] += a * wA.z; acc[i][3] += a * wA.w;                          \
        acc[i][4] += a * wB.x; acc[i][5] += a * wB.y;                          \
        acc[i][6] += a * wB.z; acc[i][7] += a * wB.w;                          \
      }                                                                        \
    }                                                                          \
  }

  PF(afA, 0)
  int t = 0;
  for (int seg = 0; seg < 2; ++seg) {
    const float* __restrict__ Wseg = seg ? W2 : W1;
    for (int k0 = 0; k0 < RNN; k0 += 16) {
      // W global loads: lane's 8 rows, this step's k-quad (wave wv -> k 4wv..+3)
      float4 gw[2][4];
#pragma unroll
      for (int c = 0; c < 2; ++c)
#pragma unroll
        for (int r = 0; r < 4; ++r)
          gw[c][r] = *(const float4*)&Wseg[(size_t)wrow[c][r] * RNN + k0 + 4 * wv];
      __syncthreads();  // previous step's readers done
#pragma unroll
      for (int c = 0; c < 2; ++c)
#pragma unroll
        for (int j = 0; j < 4; ++j) {
          *(float4*)&Ws[(4 * wv + j) * 512 + 256 * c + 4 * l] =
              make_float4(((const float*)&gw[c][0])[j],
                          ((const float*)&gw[c][1])[j],
                          ((const float*)&gw[c][2])[j],
                          ((const float*)&gw[c][3])[j]);
        }
      __syncthreads();
      // compute 4 c4-groups; A ping-pong prefetch (decoupled from barriers)
      PF(afB, t + 1) COMPUTE_C4(afA, 0)
      PF(afA, t + 2) COMPUTE_C4(afB, 1)
      PF(afB, t + 3) COMPUTE_C4(afA, 2)
      PF(afA, t + 4) COMPUTE_C4(afB, 3)
      t += 4;
    }
  }
#undef PF
#undef COMPUTE_C4

  // ---- fused LSTM epilogue (r7-verified lane-pair exchange) ----
  const int col0 = (bx << 7) + 4 * (l & 31);
  const int gA = g0;       // 0:i or 1:f
  const int gB = 2 + g0;   // 2:g or 3:o
  float bsA[4], bsB[4];
#pragma unroll
  for (int j = 0; j < 4; ++j) {
    bsA[j] = b1[gA * RNN + col0 + j] + b2[gA * RNN + col0 + j];
    bsB[j] = b1[gB * RNN + col0 + j] + b2[gB * RNN + col0 + j];
  }
  const bool low = (l < 32);
#pragma unroll
  for (int i = 0; i < 8; ++i) {
    float vA[4], vB[4], pA[4], pB[4];
#pragma unroll
    for (int j = 0; j < 4; ++j) {
      vA[j] = acc[i][j] + bsA[j];
      vB[j] = acc[i][4 + j] + bsB[j];
      pA[j] = __shfl_xor(vA[j], 32);
      pB[j] = __shfl_xor(vB[j], 32);
    }
    const bool mine = low ? (i < 4) : (i >= 4);
    if (mine) {
      const int row = rowBase + wv * 8 + i;
      const size_t off = (size_t)row * RNN + col0;
      const float4 cold = *(const float4*)&c_io[off];
      const float co[4] = {cold.x, cold.y, cold.z, cold.w};
      float cn[4], hn[4];
#pragma unroll
      for (int j = 0; j < 4; ++j) {
        const float fi = low ? vA[j] : pA[j];
        const float ff = low ? pA[j] : vA[j];
        const float fg = low ? vB[j] : pB[j];
        const float fo = low ? pB[j] : vB[j];
        const float c2 = sigmoidf_(ff) * co[j] + sigmoidf_(fi) * tanhf(fg);
        cn[j] = c2;
        hn[j] = sigmoidf_(fo) * tanhf(c2);
      }
      *(float4*)&c_io[off] = make_float4(cn[0], cn[1], cn[2], cn[3]);
      *(float4*)&h_out[off] = make_float4(hn[0], hn[1], hn[2], hn[3]);
    }
  }
}

// -------- head: logits -> +gumbel -> softmax -> hard argmax -> angle ----------
__global__ __launch_bounds__(64) void head_kernel(
    const float* __restrict__ h1, const float* __restrict__ Wang,
    const float* __restrict__ bang, float* __restrict__ angle,
    float* __restrict__ out, int s) {
  const int b = blockIdx.x;
  const int d = threadIdx.x;
  const float4* hr = (const float4*)(h1 + (size_t)b * RNN);
  const float4* wr = (const float4*)(Wang + (size_t)d * RNN);
  float acc = 0.f;
#pragma unroll 16
  for (int k = 0; k < RNN / 4; ++k) {
    float4 a = hr[k], w = wr[k];
    acc += a.x * w.x; acc += a.y * w.y; acc += a.z * w.z; acc += a.w * w.w;
  }
  float z = acc + bang[d];
  const uint32_t n = ((uint32_t)s * BATCH + (uint32_t)b) * DISC + (uint32_t)d;
  const uint32_t bits = threefry_bits(n);
  const float f = __uint_as_float((bits >> 9) | 0x3f800000u) - 1.0f;
  const float u = fmaxf(1e-8f, f + 1e-8f);
  const float gum = -logf(-logf(u));
  z += gum;
  float m = z;
#pragma unroll
  for (int off = 32; off; off >>= 1) m = fmaxf(m, __shfl_xor(m, off));
  const float e = expf(z - m);
  float ssum = e;
#pragma unroll
  for (int off = 32; off; off >>= 1) ssum += __shfl_xor(ssum, off);
  const float y = e / ssum;
  float ymax = y;
#pragma unroll
  for (int off = 32; off; off >>= 1) ymax = fmaxf(ymax, __shfl_xor(ymax, off));
  const unsigned long long mask = __ballot(y == ymax);
  const int k = __ffsll(mask) - 1;
  if (d == 0) {
    const float sp = -1.0f + (2.0f / 63.0f) * (float)k;  // linspace(-1,1,64)[k]
    angle[b] = sp;
    out[((size_t)b * NSEG + s) * 2 + 0] = sp;
    out[((size_t)b * NSEG + s) * 2 + 1] = 0.0f;
  }
}

// ------------------------------- launch ---------------------------------------
extern "C" void kernel_launch(void* const* d_in, const int* in_sizes, int n_in,
                              void* d_out, int out_size, void* d_ws, size_t ws_size,
                              hipStream_t stream) {
  const float* latent   = (const float*)d_in[0];
  const float* W_unpack = (const float*)d_in[1];
  const float* b_unpack = (const float*)d_in[2];
  const float* Wih0     = (const float*)d_in[3];
  const float* Whh0     = (const float*)d_in[4];
  const float* bih0     = (const float*)d_in[5];
  const float* bhh0     = (const float*)d_in[6];
  const float* Wih1     = (const float*)d_in[7];
  const float* Whh1     = (const float*)d_in[8];
  const float* bih1     = (const float*)d_in[9];
  const float* bhh1     = (const float*)d_in[10];
  const float* W_angle  = (const float*)d_in[11];
  const float* b_angle  = (const float*)d_in[12];
  float* out = (float*)d_out;

  const size_t HC = (size_t)BATCH * RNN;  // 2M floats
  float* ws    = (float*)d_ws;
  float* h0a   = ws;
  float* h1a   = h0a + HC;
  float* c0    = h1a + HC;
  float* c1    = c0 + HC;
  float* angle = c1 + HC;                 // BATCH floats
  float* h0b   = angle + BATCH;
  float* h1b   = h0b + HC;
  float* x     = h1b + HC;
  float* base  = x + (size_t)BATCH * CODE;

  // zero the step-0-read state: h0a, h1a, c0, c1, angle (contiguous)
  hipMemsetAsync(ws, 0, (4 * HC + BATCH) * sizeof(float), stream);

  base_kernel<<<BATCH, 256, 0, stream>>>(latent, W_unpack, b_unpack, base);

  dim3 ggrid(4, 128);
  for (int s = 0; s < NSEG; ++s) {
    const int p = s & 1;
    float* h0p = p ? h0b : h0a; float* h0n = p ? h0a : h0b;
    float* h1p = p ? h1b : h1a; float* h1n = p ? h1a : h1b;
    x_kernel<<<(BATCH * CODE) / 256, 256, 0, stream>>>(base, angle, W_unpack, x);
    gemm_lstm<<<ggrid, 256, 0, stream>>>(x, Wih0, h0p, Whh0, bih0, bhh0, c0, h0n);
    gemm_lstm<<<ggrid, 256, 0, stream>>>(h0n, Wih1, h1p, Whh1, bih1, bhh1, c1, h1n);
    head_kernel<<<BATCH, 64, 0, stream>>>(h1n, W_angle, b_angle, angle, out, s);
  }
}

// Round 10
// 35489.688 us; speedup vs baseline: 4.5572x; 4.5572x over previous
//
#include <hip/hip_runtime.h>
#include <cstdint>

#define BATCH 4096
#define LATENT 128
#define RNN 512
#define CODE 512
#define DISC 64
#define NSEG 64
#define UNPACK_COLS 130  // LATENT + INPUT

// ------------- threefry2x32, JAX partitionable mode, key = (0, 42) -----------
__device__ __forceinline__ uint32_t rotl32(uint32_t x, uint32_t r) {
  return (x << r) | (x >> (32u - r));
}

__device__ __forceinline__ uint32_t threefry_bits(uint32_t n) {
  const uint32_t k0 = 0u, k1 = 42u;
  const uint32_t ks2 = k0 ^ k1 ^ 0x1BD11BDAu;
  uint32_t x0 = 0u, x1 = n;
  x0 += k0; x1 += k1;
#define TF_ROUND(r) { x0 += x1; x1 = rotl32(x1, r); x1 ^= x0; }
  TF_ROUND(13) TF_ROUND(15) TF_ROUND(26) TF_ROUND(6)
  x0 += k1;  x1 += ks2 + 1u;
  TF_ROUND(17) TF_ROUND(29) TF_ROUND(16) TF_ROUND(24)
  x0 += ks2; x1 += k0 + 2u;
  TF_ROUND(13) TF_ROUND(15) TF_ROUND(26) TF_ROUND(6)
  x0 += k0;  x1 += k1 + 3u;
  TF_ROUND(17) TF_ROUND(29) TF_ROUND(16) TF_ROUND(24)
  x0 += k1;  x1 += ks2 + 4u;
  TF_ROUND(13) TF_ROUND(15) TF_ROUND(26) TF_ROUND(6)
  x0 += ks2; x1 += k0 + 5u;
#undef TF_ROUND
  return x0 ^ x1;
}

__device__ __forceinline__ float sigmoidf_(float v) {
  return 1.0f / (1.0f + expf(-v));
}

// ---------------- base = latent @ W_unpack[:, :128]^T + b_unpack --------------
__global__ __launch_bounds__(256) void base_kernel(
    const float* __restrict__ latent, const float* __restrict__ Wu,
    const float* __restrict__ bu, float* __restrict__ base) {
  __shared__ float lrow[LATENT];
  const int b = blockIdx.x;
  if (threadIdx.x < LATENT) lrow[threadIdx.x] = latent[b * LATENT + threadIdx.x];
  __syncthreads();
  for (int n = threadIdx.x; n < CODE; n += 256) {
    const float* wr = Wu + (size_t)n * UNPACK_COLS;
    float acc = 0.f;
#pragma unroll 8
    for (int k = 0; k < LATENT; ++k) acc += lrow[k] * wr[k];
    base[(size_t)b * CODE + n] = acc + bu[n];
  }
}

// ---------------- x = tanh(base + angle * W_unpack[:, 128]) -------------------
__global__ __launch_bounds__(256) void x_kernel(
    const float* __restrict__ base, const float* __restrict__ angle,
    const float* __restrict__ Wu, float* __restrict__ xo) {
  const int idx = blockIdx.x * 256 + threadIdx.x;
  const int b = idx >> 9;
  const int n = idx & 511;
  xo[idx] = tanhf(base[idx] + angle[b] * Wu[(size_t)n * UNPACK_COLS + 128]);
}

// ----- fused: gates = A1@W1^T + A2@W2^T + b1 + b2 ; (h,c) = LSTM(gates, c) ----
// r3's proven kernel + LDS double-buffer: ONE barrier per 16-k step (was 2),
// with global loads for step s+2 in flight under compute of step s.
// Same K-major swizzled LDS layout (col = row ^ (q<<3)), same gate-tiled N
// mapping, same epilogue.  k ascending, seg-major per output element:
// accumulation order bit-identical to rounds 2-9.
#define BM 128
#define BN 128
#define BK 16
#define KSTEPS 64  // 2 segs * (512/16)

__global__ __launch_bounds__(256) void gemm_lstm(
    const float* __restrict__ A1, const float* __restrict__ W1,
    const float* __restrict__ A2, const float* __restrict__ W2,
    const float* __restrict__ b1, const float* __restrict__ b2,
    float* __restrict__ c_io, float* __restrict__ h_out) {
  const int K = RNN;
  __shared__ __align__(16) float As[2][BK][BM];
  __shared__ __align__(16) float Ws[2][BK][BN];
  const int tid = threadIdx.x;
  const int tx = tid & 15, ty = tid >> 4;
  const int bx = blockIdx.x;            // 16 N-tiles of (4 gates x 32 cols)
  const int rowBase = blockIdx.y * BM;
  const int lrow = tid >> 2;            // 0..63
  const int lk = (tid & 3) * 4;         // k sub-offset 0,4,8,12
  const int swz = (tid & 3) << 3;       // swizzle for stored rows lk..lk+3

  int arow[2], wn[2], cc[2];
#pragma unroll
  for (int r = 0; r < 2; ++r) {
    const int rr = lrow + r * 64;
    arow[r] = rowBase + rr;
    wn[r] = ((rr >> 5) * RNN) + (bx << 5) + (rr & 31);
    cc[r] = rr ^ swz;
  }

  float acc[8][8];
#pragma unroll
  for (int i = 0; i < 8; ++i)
#pragma unroll
    for (int j = 0; j < 8; ++j) acc[i][j] = 0.f;

  float4 va[2], vw[2];  // staging regs for one upcoming step

#define LOADR(step)                                                            \
  {                                                                            \
    const float* __restrict__ A_ = ((step)&32) ? A2 : A1;                      \
    const float* __restrict__ W_ = ((step)&32) ? W2 : W1;                      \
    const int k0_ = ((step)&31) * BK;                                          \
    _Pragma("unroll") for (int r = 0; r < 2; ++r) {                            \
      va[r] = *(const float4*)&A_[(size_t)arow[r] * K + k0_ + lk];             \
      vw[r] = *(const float4*)&W_[(size_t)wn[r] * K + k0_ + lk];               \
    }                                                                          \
  }

#define STORER(buf)                                                            \
  {                                                                            \
    _Pragma("unroll") for (int r = 0; r < 2; ++r) {                            \
      As[buf][lk + 0][cc[r]] = va[r].x; As[buf][lk + 1][cc[r]] = va[r].y;      \
      As[buf][lk + 2][cc[r]] = va[r].z; As[buf][lk + 3][cc[r]] = va[r].w;      \
      Ws[buf][lk + 0][cc[r]] = vw[r].x; Ws[buf][lk + 1][cc[r]] = vw[r].y;      \
      Ws[buf][lk + 2][cc[r]] = vw[r].z; Ws[buf][lk + 3][cc[r]] = vw[r].w;      \
    }                                                                          \
  }

  // prologue: buf0 <- step 0; regs <- step 1
  LOADR(0)
  STORER(0)
  LOADR(1)
  __syncthreads();

  for (int s = 0; s < KSTEPS; ++s) {
    const int cur = s & 1;
    if (s + 1 < KSTEPS) STORER(cur ^ 1)   // store step s+1 (regs) into other buf
    if (s + 2 < KSTEPS) LOADR(s + 2)      // issue loads for s+2 (fly under FMAs)
#pragma unroll
    for (int kk = 0; kk < BK; ++kk) {
      const int swk = (kk & 12) << 1;  // ((kk>>2)&3)<<3
      const float4 a0 = *(const float4*)&As[cur][kk][(ty * 4) ^ swk];
      const float4 a1 = *(const float4*)&As[cur][kk][(64 + ty * 4) ^ swk];
      const float4 w0 = *(const float4*)&Ws[cur][kk][(tx * 4) ^ swk];
      const float4 w1 = *(const float4*)&Ws[cur][kk][(64 + tx * 4) ^ swk];
      const float av[8] = {a0.x, a0.y, a0.z, a0.w, a1.x, a1.y, a1.z, a1.w};
      const float wv[8] = {w0.x, w0.y, w0.z, w0.w, w1.x, w1.y, w1.z, w1.w};
#pragma unroll
      for (int i = 0; i < 8; ++i)
#pragma unroll
        for (int j = 0; j < 8; ++j) acc[i][j] += av[i] * wv[j];
    }
    __syncthreads();
  }
#undef LOADR
#undef STORER

  // ---- fused LSTM epilogue (unchanged from round 3) ----
  const int myjl = (tx & 7) * 4;
  const int jbase = (bx << 5) + myjl;       // rnn col 0..508
  const int g0 = (tx < 8) ? 0 : 1;
  const int g1 = g0 + 2;
  float bs0[4], bs1[4];
#pragma unroll
  for (int j = 0; j < 4; ++j) {
    bs0[j] = b1[g0 * RNN + jbase + j] + b2[g0 * RNN + jbase + j];
    bs1[j] = b1[g1 * RNN + jbase + j] + b2[g1 * RNN + jbase + j];
  }
  const bool low = (tx < 8);
#pragma unroll
  for (int i = 0; i < 8; ++i) {
    float v0[4], v1[4], p0[4], p1[4];
#pragma unroll
    for (int j = 0; j < 4; ++j) {
      v0[j] = acc[i][j] + bs0[j];
      v1[j] = acc[i][4 + j] + bs1[j];
      p0[j] = __shfl_xor(v0[j], 8);
      p1[j] = __shfl_xor(v1[j], 8);
    }
    const bool mine = low ? (i < 4) : (i >= 4);
    if (mine) {
      const int row = rowBase + (low ? (ty * 4 + i) : (64 + ty * 4 + (i - 4)));
      const size_t off = (size_t)row * RNN + jbase;
      const float4 cold = *(const float4*)&c_io[off];
      const float co[4] = {cold.x, cold.y, cold.z, cold.w};
      float cn[4], hn[4];
#pragma unroll
      for (int j = 0; j < 4; ++j) {
        const float fi = low ? v0[j] : p0[j];
        const float fg = low ? v1[j] : p1[j];
        const float ff = low ? p0[j] : v0[j];
        const float fo = low ? p1[j] : v1[j];
        const float c2 = sigmoidf_(ff) * co[j] + sigmoidf_(fi) * tanhf(fg);
        cn[j] = c2;
        hn[j] = sigmoidf_(fo) * tanhf(c2);
      }
      *(float4*)&c_io[off] = make_float4(cn[0], cn[1], cn[2], cn[3]);
      *(float4*)&h_out[off] = make_float4(hn[0], hn[1], hn[2], hn[3]);
    }
  }
}

// -------- head: logits -> +gumbel -> softmax -> hard argmax -> angle ----------
__global__ __launch_bounds__(64) void head_kernel(
    const float* __restrict__ h1, const float* __restrict__ Wang,
    const float* __restrict__ bang, float* __restrict__ angle,
    float* __restrict__ out, int s) {
  const int b = blockIdx.x;
  const int d = threadIdx.x;
  const float4* hr = (const float4*)(h1 + (size_t)b * RNN);
  const float4* wr = (const float4*)(Wang + (size_t)d * RNN);
  float acc = 0.f;
#pragma unroll 16
  for (int k = 0; k < RNN / 4; ++k) {
    float4 a = hr[k], w = wr[k];
    acc += a.x * w.x; acc += a.y * w.y; acc += a.z * w.z; acc += a.w * w.w;
  }
  float z = acc + bang[d];
  const uint32_t n = ((uint32_t)s * BATCH + (uint32_t)b) * DISC + (uint32_t)d;
  const uint32_t bits = threefry_bits(n);
  const float f = __uint_as_float((bits >> 9) | 0x3f800000u) - 1.0f;
  const float u = fmaxf(1e-8f, f + 1e-8f);
  const float gum = -logf(-logf(u));
  z += gum;
  float m = z;
#pragma unroll
  for (int off = 32; off; off >>= 1) m = fmaxf(m, __shfl_xor(m, off));
  const float e = expf(z - m);
  float ssum = e;
#pragma unroll
  for (int off = 32; off; off >>= 1) ssum += __shfl_xor(ssum, off);
  const float y = e / ssum;
  float ymax = y;
#pragma unroll
  for (int off = 32; off; off >>= 1) ymax = fmaxf(ymax, __shfl_xor(ymax, off));
  const unsigned long long mask = __ballot(y == ymax);
  const int k = __ffsll(mask) - 1;
  if (d == 0) {
    const float sp = -1.0f + (2.0f / 63.0f) * (float)k;  // linspace(-1,1,64)[k]
    angle[b] = sp;
    out[((size_t)b * NSEG + s) * 2 + 0] = sp;
    out[((size_t)b * NSEG + s) * 2 + 1] = 0.0f;
  }
}

// ------------------------------- launch ---------------------------------------
extern "C" void kernel_launch(void* const* d_in, const int* in_sizes, int n_in,
                              void* d_out, int out_size, void* d_ws, size_t ws_size,
                              hipStream_t stream) {
  const float* latent   = (const float*)d_in[0];
  const float* W_unpack = (const float*)d_in[1];
  const float* b_unpack = (const float*)d_in[2];
  const float* Wih0     = (const float*)d_in[3];
  const float* Whh0     = (const float*)d_in[4];
  const float* bih0     = (const float*)d_in[5];
  const float* bhh0     = (const float*)d_in[6];
  const float* Wih1     = (const float*)d_in[7];
  const float* Whh1     = (const float*)d_in[8];
  const float* bih1     = (const float*)d_in[9];
  const float* bhh1     = (const float*)d_in[10];
  const float* W_angle  = (const float*)d_in[11];
  const float* b_angle  = (const float*)d_in[12];
  float* out = (float*)d_out;

  const size_t HC = (size_t)BATCH * RNN;  // 2M floats
  float* ws    = (float*)d_ws;
  float* h0a   = ws;
  float* h1a   = h0a + HC;
  float* c0    = h1a + HC;
  float* c1    = c0 + HC;
  float* angle = c1 + HC;                 // BATCH floats
  float* h0b   = angle + BATCH;
  float* h1b   = h0b + HC;
  float* x     = h1b + HC;
  float* base  = x + (size_t)BATCH * CODE;

  // zero the step-0-read state: h0a, h1a, c0, c1, angle (contiguous)
  hipMemsetAsync(ws, 0, (4 * HC + BATCH) * sizeof(float), stream);

  base_kernel<<<BATCH, 256, 0, stream>>>(latent, W_unpack, b_unpack, base);

  dim3 ggrid(16, 32);
  for (int s = 0; s < NSEG; ++s) {
    const int p = s & 1;
    float* h0p = p ? h0b : h0a; float* h0n = p ? h0a : h0b;
    float* h1p = p ? h1b : h1a; float* h1n = p ? h1a : h1b;
    x_kernel<<<(BATCH * CODE) / 256, 256, 0, stream>>>(base, angle, W_unpack, x);
    gemm_lstm<<<ggrid, 256, 0, stream>>>(x, Wih0, h0p, Whh0, bih0, bhh0, c0, h0n);
    gemm_lstm<<<ggrid, 256, 0, stream>>>(h0n, Wih1, h1p, Whh1, bih1, bhh1, c1, h1n);
    head_kernel<<<BATCH, 64, 0, stream>>>(h1n, W_angle, b_angle, angle, out, s);
  }
}